// Round 1
// baseline (1069.910 us; speedup 1.0000x reference)
//
#include <hip/hip_runtime.h>

#define B_ 4
#define L_ 512
#define D_ 1024
#define E_ 16
#define K_ 4
#define F_ 4096
#define NTOK (B_*L_)      // 2048
#define NPAIR (NTOK*K_)   // 8192

typedef float f32x4 __attribute__((ext_vector_type(4)));
typedef __bf16 bf16x8 __attribute__((ext_vector_type(8)));

__device__ inline unsigned int pack2(float a, float b) {
    unsigned short ua = __builtin_bit_cast(unsigned short, (__bf16)a);
    unsigned short ub = __builtin_bit_cast(unsigned short, (__bf16)b);
    return (unsigned int)ua | ((unsigned int)ub << 16);
}

// ---------------- Router: logits = -||x-key||^2 + x.rw + rb ; top-4 + softmax ----------------
__global__ __launch_bounds__(256) void router_kernel(
    const float* __restrict__ x, const float* __restrict__ keys,
    const float* __restrict__ rw, const float* __restrict__ rb,
    int* __restrict__ topi, float* __restrict__ topw, int* __restrict__ counts)
{
    int t = blockIdx.x;
    int tid = threadIdx.x;
    if (blockIdx.x == 0 && tid < E_) counts[tid] = 0;   // zero counts for bucket pass

    __shared__ float xs[D_];
    const float* xrow = x + (size_t)t * D_;
    for (int i = tid; i < D_; i += 256) xs[i] = xrow[i];
    __syncthreads();

    int e    = tid >> 4;     // 16 threads per expert
    int lane = tid & 15;
    const float* krow = keys + e * D_;
    const float* rrow = rw   + e * D_;
    double dist2 = 0.0, dot = 0.0;
    for (int d = lane; d < D_; d += 16) {
        float xv = xs[d];
        float df = xv - krow[d];
        dist2 += (double)df * df;
        dot   += (double)xv * rrow[d];
    }
    #pragma unroll
    for (int m = 8; m >= 1; m >>= 1) {
        dist2 += __shfl_xor(dist2, m);
        dot   += __shfl_xor(dot, m);
    }
    __shared__ float lg[E_];
    if (lane == 0) lg[e] = (float)(-dist2 + dot) + rb[e];
    __syncthreads();

    if (tid == 0) {
        float v[E_];
        #pragma unroll
        for (int i = 0; i < E_; i++) v[i] = lg[i];
        int   idx[K_]; float val[K_];
        #pragma unroll
        for (int k = 0; k < K_; k++) {
            int bi = 0; float bv = -1e30f;
            #pragma unroll
            for (int i = 0; i < E_; i++) if (v[i] > bv) { bv = v[i]; bi = i; }
            idx[k] = bi; val[k] = bv; v[bi] = -1e30f;
        }
        float mx = val[0], s = 0.f, w[K_];
        #pragma unroll
        for (int k = 0; k < K_; k++) { w[k] = expf(val[k] - mx); s += w[k]; }
        float inv = 1.0f / s;
        #pragma unroll
        for (int k = 0; k < K_; k++) {
            topi[t*K_ + k] = idx[k];
            topw[t*K_ + k] = w[k] * inv;
        }
    }
}

// ---------------- Bucket tokens by expert ----------------
__global__ void bucket_kernel(const int* __restrict__ topi, const float* __restrict__ topw,
                              int* __restrict__ counts,
                              int* __restrict__ bucket_tok, float* __restrict__ bucket_w)
{
    int i = blockIdx.x * 256 + threadIdx.x;
    if (i >= NPAIR) return;
    int t = i >> 2;
    int e = topi[i];
    int pos = atomicAdd(&counts[e], 1);
    bucket_tok[e * NTOK + pos] = t;
    bucket_w [e * NTOK + pos] = topw[i];
}

__global__ void scan_kernel(const int* __restrict__ counts, int* __restrict__ offsets)
{
    if (threadIdx.x == 0) {
        int s = 0;
        for (int e = 0; e < E_; e++) { offsets[e] = s; s += counts[e]; }
        offsets[E_] = s;
    }
}

// ---------------- GEMM1: hidden = gelu(x_g @ w1^T + b1), bf16 out ----------------
// tile 128 tokens x 128 F, TK=32; 4 waves (2x2), each 64x64 (4x4 MFMA 16x16x32)
__global__ __launch_bounds__(256) void gemm1_kernel(
    const float* __restrict__ x, const float* __restrict__ w1, const float* __restrict__ b1,
    const int* __restrict__ counts, const int* __restrict__ offsets,
    const int* __restrict__ bucket_tok, unsigned short* __restrict__ hidden)
{
    int e  = blockIdx.z;
    int Te = counts[e];
    int row0 = blockIdx.y * 128;
    if (row0 >= Te) return;
    int f0 = blockIdx.x * 128;
    int tid = threadIdx.x;

    __shared__ unsigned short As[128][40];   // pad 32->40 (2-way max conflict on b128 reads)
    __shared__ unsigned short Bs[128][40];
    __shared__ int toks[128];

    if (tid < 128) {
        int r = row0 + tid;
        toks[tid] = bucket_tok[e * NTOK + (r < Te ? r : Te - 1)];
    }
    __syncthreads();

    int lane = tid & 63, wave = tid >> 6;
    int wr = wave >> 1, wc = wave & 1;
    int lr = lane & 15;
    int ko = (lane >> 4) * 8;

    f32x4 acc[4][4];
    #pragma unroll
    for (int m = 0; m < 4; m++)
        #pragma unroll
        for (int n = 0; n < 4; n++) acc[m][n] = (f32x4){0.f, 0.f, 0.f, 0.f};

    int sr = tid >> 1;          // staging row 0..127
    int sc = (tid & 1) * 16;    // staging col 0 or 16

    for (int k0 = 0; k0 < D_; k0 += 32) {
        { // A: gathered x rows, fp32 -> bf16
            const float4* s4 = reinterpret_cast<const float4*>(x + (size_t)toks[sr] * D_ + k0 + sc);
            float4 a0 = s4[0], a1 = s4[1], a2 = s4[2], a3 = s4[3];
            uint4 p0 = { pack2(a0.x,a0.y), pack2(a0.z,a0.w), pack2(a1.x,a1.y), pack2(a1.z,a1.w) };
            uint4 p1 = { pack2(a2.x,a2.y), pack2(a2.z,a2.w), pack2(a3.x,a3.y), pack2(a3.z,a3.w) };
            *reinterpret_cast<uint4*>(&As[sr][sc])     = p0;
            *reinterpret_cast<uint4*>(&As[sr][sc + 8]) = p1;
        }
        { // B: w1[e][f][:] rows, fp32 -> bf16
            const float4* s4 = reinterpret_cast<const float4*>(w1 + ((size_t)e * F_ + f0 + sr) * D_ + k0 + sc);
            float4 a0 = s4[0], a1 = s4[1], a2 = s4[2], a3 = s4[3];
            uint4 p0 = { pack2(a0.x,a0.y), pack2(a0.z,a0.w), pack2(a1.x,a1.y), pack2(a1.z,a1.w) };
            uint4 p1 = { pack2(a2.x,a2.y), pack2(a2.z,a2.w), pack2(a3.x,a3.y), pack2(a3.z,a3.w) };
            *reinterpret_cast<uint4*>(&Bs[sr][sc])     = p0;
            *reinterpret_cast<uint4*>(&Bs[sr][sc + 8]) = p1;
        }
        __syncthreads();
        bf16x8 a[4], b[4];
        #pragma unroll
        for (int m = 0; m < 4; m++) a[m] = *reinterpret_cast<const bf16x8*>(&As[wr*64 + m*16 + lr][ko]);
        #pragma unroll
        for (int n = 0; n < 4; n++) b[n] = *reinterpret_cast<const bf16x8*>(&Bs[wc*64 + n*16 + lr][ko]);
        #pragma unroll
        for (int m = 0; m < 4; m++)
            #pragma unroll
            for (int n = 0; n < 4; n++)
                acc[m][n] = __builtin_amdgcn_mfma_f32_16x16x32_bf16(a[m], b[n], acc[m][n], 0, 0, 0);
        __syncthreads();
    }

    int obase = offsets[e];
    #pragma unroll
    for (int m = 0; m < 4; m++) {
        int rbase = wr*64 + m*16 + (lane >> 4) * 4;
        #pragma unroll
        for (int n = 0; n < 4; n++) {
            int gcol = f0 + wc*64 + n*16 + lr;
            float bias = b1[e * F_ + gcol];
            #pragma unroll
            for (int r = 0; r < 4; r++) {
                int lrow = rbase + r;
                if (row0 + lrow < Te) {
                    float v = acc[m][n][r] + bias;
                    float g = 0.5f * v * (1.0f + erff(v * 0.70710678118654752f));
                    hidden[(size_t)(obase + row0 + lrow) * F_ + gcol] =
                        __builtin_bit_cast(unsigned short, (__bf16)g);
                }
            }
        }
    }
}

// ---------------- GEMM2: out += gate_w * (hidden @ w2^T + b2), atomic scatter ----------------
__global__ __launch_bounds__(256) void gemm2_kernel(
    const unsigned short* __restrict__ hidden, const float* __restrict__ w2, const float* __restrict__ b2,
    const int* __restrict__ counts, const int* __restrict__ offsets,
    const int* __restrict__ bucket_tok, const float* __restrict__ bucket_w,
    float* __restrict__ out)
{
    int e  = blockIdx.z;
    int Te = counts[e];
    int row0 = blockIdx.y * 128;
    if (row0 >= Te) return;
    int n0 = blockIdx.x * 128;
    int tid = threadIdx.x;

    __shared__ unsigned short As[128][40];
    __shared__ unsigned short Bs[128][40];
    __shared__ int   toks[128];
    __shared__ float wts [128];

    if (tid < 128) {
        int r = row0 + tid;
        int rc = (r < Te ? r : Te - 1);
        toks[tid] = bucket_tok[e * NTOK + rc];
        wts [tid] = bucket_w [e * NTOK + rc];
    }
    __syncthreads();

    int lane = tid & 63, wave = tid >> 6;
    int wr = wave >> 1, wc = wave & 1;
    int lr = lane & 15;
    int ko = (lane >> 4) * 8;

    f32x4 acc[4][4];
    #pragma unroll
    for (int m = 0; m < 4; m++)
        #pragma unroll
        for (int n = 0; n < 4; n++) acc[m][n] = (f32x4){0.f, 0.f, 0.f, 0.f};

    int sr = tid >> 1;
    int sc = (tid & 1) * 16;
    int obase = offsets[e];
    int arow = row0 + sr; arow = (arow < Te ? arow : Te - 1);
    const uint4* asrc_base = reinterpret_cast<const uint4*>(hidden + (size_t)(obase + arow) * F_);

    for (int k0 = 0; k0 < F_; k0 += 32) {
        { // A: hidden rows (already bf16)
            const uint4* s = reinterpret_cast<const uint4*>(
                reinterpret_cast<const unsigned short*>(asrc_base) + k0 + sc);
            uint4 p0 = s[0], p1 = s[1];
            *reinterpret_cast<uint4*>(&As[sr][sc])     = p0;
            *reinterpret_cast<uint4*>(&As[sr][sc + 8]) = p1;
        }
        { // B: w2[e][d][:] rows, fp32 -> bf16
            const float4* s4 = reinterpret_cast<const float4*>(w2 + ((size_t)e * D_ + n0 + sr) * F_ + k0 + sc);
            float4 a0 = s4[0], a1 = s4[1], a2 = s4[2], a3 = s4[3];
            uint4 p0 = { pack2(a0.x,a0.y), pack2(a0.z,a0.w), pack2(a1.x,a1.y), pack2(a1.z,a1.w) };
            uint4 p1 = { pack2(a2.x,a2.y), pack2(a2.z,a2.w), pack2(a3.x,a3.y), pack2(a3.z,a3.w) };
            *reinterpret_cast<uint4*>(&Bs[sr][sc])     = p0;
            *reinterpret_cast<uint4*>(&Bs[sr][sc + 8]) = p1;
        }
        __syncthreads();
        bf16x8 a[4], b[4];
        #pragma unroll
        for (int m = 0; m < 4; m++) a[m] = *reinterpret_cast<const bf16x8*>(&As[wr*64 + m*16 + lr][ko]);
        #pragma unroll
        for (int n = 0; n < 4; n++) b[n] = *reinterpret_cast<const bf16x8*>(&Bs[wc*64 + n*16 + lr][ko]);
        #pragma unroll
        for (int m = 0; m < 4; m++)
            #pragma unroll
            for (int n = 0; n < 4; n++)
                acc[m][n] = __builtin_amdgcn_mfma_f32_16x16x32_bf16(a[m], b[n], acc[m][n], 0, 0, 0);
        __syncthreads();
    }

    #pragma unroll
    for (int m = 0; m < 4; m++) {
        int rbase = wr*64 + m*16 + (lane >> 4) * 4;
        #pragma unroll
        for (int n = 0; n < 4; n++) {
            int gcol = n0 + wc*64 + n*16 + lr;
            float bias = b2[e * D_ + gcol];
            #pragma unroll
            for (int r = 0; r < 4; r++) {
                int lrow = rbase + r;
                if (row0 + lrow < Te) {
                    float v = acc[m][n][r] + bias;
                    atomicAdd(&out[(size_t)toks[lrow] * D_ + gcol], wts[lrow] * v);
                }
            }
        }
    }
}

extern "C" void kernel_launch(void* const* d_in, const int* in_sizes, int n_in,
                              void* d_out, int out_size, void* d_ws, size_t ws_size,
                              hipStream_t stream)
{
    const float* x    = (const float*)d_in[0];
    const float* keys = (const float*)d_in[1];
    const float* w1   = (const float*)d_in[2];
    const float* b1   = (const float*)d_in[3];
    const float* w2   = (const float*)d_in[4];
    const float* b2   = (const float*)d_in[5];
    const float* rw   = (const float*)d_in[6];
    const float* rb   = (const float*)d_in[7];
    float* out = (float*)d_out;

    char* wsp = (char*)d_ws;
    size_t off = 0;
    auto alloc = [&](size_t bytes) -> char* {
        char* p = wsp + off;
        off = (off + bytes + 255) & ~(size_t)255;
        return p;
    };
    int*   topi       = (int*)  alloc(NPAIR * sizeof(int));
    float* topw       = (float*)alloc(NPAIR * sizeof(float));
    int*   counts     = (int*)  alloc(E_ * sizeof(int));
    int*   offsets    = (int*)  alloc((E_ + 1) * sizeof(int));
    int*   bucket_tok = (int*)  alloc((size_t)E_ * NTOK * sizeof(int));
    float* bucket_w   = (float*)alloc((size_t)E_ * NTOK * sizeof(float));
    unsigned short* hidden = (unsigned short*)alloc((size_t)NPAIR * F_ * sizeof(unsigned short)); // 64 MB

    hipMemsetAsync(d_out, 0, (size_t)out_size * sizeof(float), stream);

    router_kernel<<<NTOK, 256, 0, stream>>>(x, keys, rw, rb, topi, topw, counts);
    bucket_kernel<<<NPAIR / 256, 256, 0, stream>>>(topi, topw, counts, bucket_tok, bucket_w);
    scan_kernel<<<1, 64, 0, stream>>>(counts, offsets);
    gemm1_kernel<<<dim3(F_ / 128, NTOK / 128, E_), 256, 0, stream>>>(
        x, w1, b1, counts, offsets, bucket_tok, hidden);
    gemm2_kernel<<<dim3(D_ / 128, NTOK / 128, E_), 256, 0, stream>>>(
        hidden, w2, b2, counts, offsets, bucket_tok, bucket_w, out);
}

// Round 4
// 993.453 us; speedup vs baseline: 1.0770x; 1.0770x over previous
//
#include <hip/hip_runtime.h>

#define B_ 4
#define L_ 512
#define D_ 1024
#define E_ 16
#define K_ 4
#define F_ 4096
#define NTOK (B_*L_)      // 2048
#define NPAIR (NTOK*K_)   // 8192

typedef float f32x4 __attribute__((ext_vector_type(4)));
typedef __bf16 bf16x8 __attribute__((ext_vector_type(8)));

__device__ inline unsigned int pack2(float a, float b) {
    unsigned short ua = __builtin_bit_cast(unsigned short, (__bf16)a);
    unsigned short ub = __builtin_bit_cast(unsigned short, (__bf16)b);
    return (unsigned int)ua | ((unsigned int)ub << 16);
}

#define GLOAD16(g, l) __builtin_amdgcn_global_load_lds( \
    (const __attribute__((address_space(1))) void*)(g), \
    (__attribute__((address_space(3))) void*)(l), 16, 0, 0)

// ---------------- fp32 -> bf16 bulk convert (16 elems/thread) ----------------
__global__ __launch_bounds__(256) void cvt_kernel(const float* __restrict__ src,
                                                  unsigned short* __restrict__ dst)
{
    size_t i = ((size_t)blockIdx.x * 256 + threadIdx.x) * 16;
    const float4* s = reinterpret_cast<const float4*>(src + i);
    float4 v0 = s[0], v1 = s[1], v2 = s[2], v3 = s[3];
    uint4 p0 = { pack2(v0.x,v0.y), pack2(v0.z,v0.w), pack2(v1.x,v1.y), pack2(v1.z,v1.w) };
    uint4 p1 = { pack2(v2.x,v2.y), pack2(v2.z,v2.w), pack2(v3.x,v3.y), pack2(v3.z,v3.w) };
    uint4* d = reinterpret_cast<uint4*>(dst + i);
    d[0] = p0; d[1] = p1;
}

// ---------------- Router: logits = -||x-key||^2 + x.rw + rb ; top-4 + softmax ----------------
__global__ __launch_bounds__(256) void router_kernel(
    const float* __restrict__ x, const float* __restrict__ keys,
    const float* __restrict__ rw, const float* __restrict__ rb,
    int* __restrict__ topi, float* __restrict__ topw, int* __restrict__ counts)
{
    int t = blockIdx.x;
    int tid = threadIdx.x;
    if (blockIdx.x == 0 && tid < E_) counts[tid] = 0;

    __shared__ float xs[D_];
    const float* xrow = x + (size_t)t * D_;
    for (int i = tid; i < D_; i += 256) xs[i] = xrow[i];
    __syncthreads();

    int e    = tid >> 4;     // 16 threads per expert
    int lane = tid & 15;
    const float* krow = keys + e * D_;
    const float* rrow = rw   + e * D_;
    double dist2 = 0.0, dot = 0.0;
    for (int d = lane; d < D_; d += 16) {
        float xv = xs[d];
        float df = xv - krow[d];
        dist2 += (double)df * df;
        dot   += (double)xv * rrow[d];
    }
    #pragma unroll
    for (int m = 8; m >= 1; m >>= 1) {
        dist2 += __shfl_xor(dist2, m);
        dot   += __shfl_xor(dot, m);
    }
    __shared__ float lg[E_];
    if (lane == 0) lg[e] = (float)(-dist2 + dot) + rb[e];
    __syncthreads();

    if (tid == 0) {
        float v[E_];
        #pragma unroll
        for (int i = 0; i < E_; i++) v[i] = lg[i];
        int   idx[K_]; float val[K_];
        #pragma unroll
        for (int k = 0; k < K_; k++) {
            int bi = 0; float bv = -1e30f;
            #pragma unroll
            for (int i = 0; i < E_; i++) if (v[i] > bv) { bv = v[i]; bi = i; }
            idx[k] = bi; val[k] = bv; v[bi] = -1e30f;
        }
        float mx = val[0], s = 0.f, w[K_];
        #pragma unroll
        for (int k = 0; k < K_; k++) { w[k] = expf(val[k] - mx); s += w[k]; }
        float inv = 1.0f / s;
        #pragma unroll
        for (int k = 0; k < K_; k++) {
            topi[t*K_ + k] = idx[k];
            topw[t*K_ + k] = w[k] * inv;
        }
    }
}

// ---------------- Bucket tokens by expert ----------------
__global__ void bucket_kernel(const int* __restrict__ topi, const float* __restrict__ topw,
                              int* __restrict__ counts,
                              int* __restrict__ bucket_tok, float* __restrict__ bucket_w)
{
    int i = blockIdx.x * 256 + threadIdx.x;
    if (i >= NPAIR) return;
    int t = i >> 2;
    int e = topi[i];
    int pos = atomicAdd(&counts[e], 1);
    bucket_tok[e * NTOK + pos] = t;
    bucket_w [e * NTOK + pos] = topw[i];
}

__global__ void scan_kernel(const int* __restrict__ counts, int* __restrict__ offsets)
{
    if (threadIdx.x == 0) {
        int s = 0;
        for (int e = 0; e < E_; e++) { offsets[e] = s; s += counts[e]; }
        offsets[E_] = s;
    }
}

// ---------------- GEMM1: hidden = gelu(x_g @ w1^T + b1), bf16 out ----------------
// m97 structure: 128x128 tile, BK=32, linear LDS, global_load_lds width=16.
__global__ __launch_bounds__(256) void gemm1_kernel(
    const unsigned short* __restrict__ xb, const unsigned short* __restrict__ w1b,
    const float* __restrict__ b1,
    const int* __restrict__ counts, const int* __restrict__ offsets,
    const int* __restrict__ bucket_tok, unsigned short* __restrict__ hidden)
{
    int e  = blockIdx.z;
    int Te = counts[e];
    int row0 = blockIdx.y * 128;
    if (row0 >= Te) return;
    int f0 = blockIdx.x * 128;
    int tid = threadIdx.x;
    int lane = tid & 63, wave = tid >> 6;

    __shared__ unsigned short As[128][32];
    __shared__ unsigned short Bs[128][32];
    __shared__ int toks[128];

    if (tid < 128) {
        int r = row0 + tid;
        toks[tid] = bucket_tok[e * NTOK + (r < Te ? r : Te - 1)];
    }
    __syncthreads();

    // staging: wave w owns chunks {2w, 2w+1}; chunk = 16 rows; lane -> row chunk*16+(l>>2), slot l&3
    int sl = lane & 3;
    int r0 = (wave * 2 + 0) * 16 + (lane >> 2);
    int r1 = (wave * 2 + 1) * 16 + (lane >> 2);
    const unsigned short* pa0 = xb + (size_t)toks[r0] * D_ + sl * 8;
    const unsigned short* pa1 = xb + (size_t)toks[r1] * D_ + sl * 8;
    const unsigned short* pb0 = w1b + ((size_t)e * F_ + f0 + r0) * D_ + sl * 8;
    const unsigned short* pb1 = w1b + ((size_t)e * F_ + f0 + r1) * D_ + sl * 8;
    unsigned short* la0 = &As[(wave * 2 + 0) * 16][0];
    unsigned short* la1 = &As[(wave * 2 + 1) * 16][0];
    unsigned short* lb0 = &Bs[(wave * 2 + 0) * 16][0];
    unsigned short* lb1 = &Bs[(wave * 2 + 1) * 16][0];

    int wr = wave >> 1, wc = wave & 1;
    int lr = lane & 15, ko = (lane >> 4) * 8;

    f32x4 acc[4][4];
    #pragma unroll
    for (int m = 0; m < 4; m++)
        #pragma unroll
        for (int n = 0; n < 4; n++) acc[m][n] = (f32x4){0.f, 0.f, 0.f, 0.f};

    for (int k0 = 0; k0 < D_; k0 += 32) {
        GLOAD16(pa0 + k0, la0);
        GLOAD16(pa1 + k0, la1);
        GLOAD16(pb0 + k0, lb0);
        GLOAD16(pb1 + k0, lb1);
        __syncthreads();
        bf16x8 a[4], b[4];
        #pragma unroll
        for (int m = 0; m < 4; m++) a[m] = *reinterpret_cast<const bf16x8*>(&As[wr*64 + m*16 + lr][ko]);
        #pragma unroll
        for (int n = 0; n < 4; n++) b[n] = *reinterpret_cast<const bf16x8*>(&Bs[wc*64 + n*16 + lr][ko]);
        #pragma unroll
        for (int m = 0; m < 4; m++)
            #pragma unroll
            for (int n = 0; n < 4; n++)
                acc[m][n] = __builtin_amdgcn_mfma_f32_16x16x32_bf16(a[m], b[n], acc[m][n], 0, 0, 0);
        __syncthreads();
    }

    int obase = offsets[e];
    #pragma unroll
    for (int m = 0; m < 4; m++) {
        int rbase = wr*64 + m*16 + (lane >> 4) * 4;
        #pragma unroll
        for (int n = 0; n < 4; n++) {
            int gcol = f0 + wc*64 + n*16 + lr;
            float bias = b1[e * F_ + gcol];
            #pragma unroll
            for (int r = 0; r < 4; r++) {
                int lrow = rbase + r;
                if (row0 + lrow < Te) {
                    float v = acc[m][n][r] + bias;
                    float g = 0.5f * v * (1.0f + erff(v * 0.70710678118654752f));
                    hidden[(size_t)(obase + row0 + lrow) * F_ + gcol] =
                        __builtin_bit_cast(unsigned short, (__bf16)g);
                }
            }
        }
    }
}

// ---------------- GEMM2: out += gate_w * (hidden @ w2^T + b2), atomic scatter ----------------
__global__ __launch_bounds__(256) void gemm2_kernel(
    const unsigned short* __restrict__ hidden, const unsigned short* __restrict__ w2b,
    const float* __restrict__ b2,
    const int* __restrict__ counts, const int* __restrict__ offsets,
    const int* __restrict__ bucket_tok, const float* __restrict__ bucket_w,
    float* __restrict__ out)
{
    int e  = blockIdx.z;
    int Te = counts[e];
    int row0 = blockIdx.y * 128;
    if (row0 >= Te) return;
    int n0 = blockIdx.x * 128;
    int tid = threadIdx.x;
    int lane = tid & 63, wave = tid >> 6;

    __shared__ unsigned short As[128][32];
    __shared__ unsigned short Bs[128][32];
    __shared__ int   toks[128];
    __shared__ float wts [128];

    int obase = offsets[e];
    if (tid < 128) {
        int r = row0 + tid;
        int rc = (r < Te ? r : Te - 1);
        toks[tid] = bucket_tok[e * NTOK + rc];
        wts [tid] = bucket_w [e * NTOK + rc];
    }
    __syncthreads();

    int sl = lane & 3;
    int r0 = (wave * 2 + 0) * 16 + (lane >> 2);
    int r1 = (wave * 2 + 1) * 16 + (lane >> 2);
    int ar0 = row0 + r0; ar0 = (ar0 < Te ? ar0 : Te - 1);
    int ar1 = row0 + r1; ar1 = (ar1 < Te ? ar1 : Te - 1);
    const unsigned short* pa0 = hidden + (size_t)(obase + ar0) * F_ + sl * 8;
    const unsigned short* pa1 = hidden + (size_t)(obase + ar1) * F_ + sl * 8;
    const unsigned short* pb0 = w2b + ((size_t)e * D_ + n0 + r0) * F_ + sl * 8;
    const unsigned short* pb1 = w2b + ((size_t)e * D_ + n0 + r1) * F_ + sl * 8;
    unsigned short* la0 = &As[(wave * 2 + 0) * 16][0];
    unsigned short* la1 = &As[(wave * 2 + 1) * 16][0];
    unsigned short* lb0 = &Bs[(wave * 2 + 0) * 16][0];
    unsigned short* lb1 = &Bs[(wave * 2 + 1) * 16][0];

    int wr = wave >> 1, wc = wave & 1;
    int lr = lane & 15, ko = (lane >> 4) * 8;

    f32x4 acc[4][4];
    #pragma unroll
    for (int m = 0; m < 4; m++)
        #pragma unroll
        for (int n = 0; n < 4; n++) acc[m][n] = (f32x4){0.f, 0.f, 0.f, 0.f};

    for (int k0 = 0; k0 < F_; k0 += 32) {
        GLOAD16(pa0 + k0, la0);
        GLOAD16(pa1 + k0, la1);
        GLOAD16(pb0 + k0, lb0);
        GLOAD16(pb1 + k0, lb1);
        __syncthreads();
        bf16x8 a[4], b[4];
        #pragma unroll
        for (int m = 0; m < 4; m++) a[m] = *reinterpret_cast<const bf16x8*>(&As[wr*64 + m*16 + lr][ko]);
        #pragma unroll
        for (int n = 0; n < 4; n++) b[n] = *reinterpret_cast<const bf16x8*>(&Bs[wc*64 + n*16 + lr][ko]);
        #pragma unroll
        for (int m = 0; m < 4; m++)
            #pragma unroll
            for (int n = 0; n < 4; n++)
                acc[m][n] = __builtin_amdgcn_mfma_f32_16x16x32_bf16(a[m], b[n], acc[m][n], 0, 0, 0);
        __syncthreads();
    }

    #pragma unroll
    for (int m = 0; m < 4; m++) {
        int rbase = wr*64 + m*16 + (lane >> 4) * 4;
        #pragma unroll
        for (int n = 0; n < 4; n++) {
            int gcol = n0 + wc*64 + n*16 + lr;
            float bias = b2[e * D_ + gcol];
            #pragma unroll
            for (int r = 0; r < 4; r++) {
                int lrow = rbase + r;
                if (row0 + lrow < Te) {
                    float v = acc[m][n][r] + bias;
                    atomicAdd(&out[(size_t)toks[lrow] * D_ + gcol], wts[lrow] * v);
                }
            }
        }
    }
}

extern "C" void kernel_launch(void* const* d_in, const int* in_sizes, int n_in,
                              void* d_out, int out_size, void* d_ws, size_t ws_size,
                              hipStream_t stream)
{
    const float* x    = (const float*)d_in[0];
    const float* keys = (const float*)d_in[1];
    const float* w1   = (const float*)d_in[2];
    const float* b1   = (const float*)d_in[3];
    const float* w2   = (const float*)d_in[4];
    const float* b2   = (const float*)d_in[5];
    const float* rw   = (const float*)d_in[6];
    const float* rb   = (const float*)d_in[7];
    float* out = (float*)d_out;

    char* wsp = (char*)d_ws;
    size_t off = 0;
    auto alloc = [&](size_t bytes) -> char* {
        char* p = wsp + off;
        off = (off + bytes + 255) & ~(size_t)255;
        return p;
    };
    int*   topi       = (int*)  alloc(NPAIR * sizeof(int));
    float* topw       = (float*)alloc(NPAIR * sizeof(float));
    int*   counts     = (int*)  alloc(E_ * sizeof(int));
    int*   offsets    = (int*)  alloc((E_ + 1) * sizeof(int));
    int*   bucket_tok = (int*)  alloc((size_t)E_ * NTOK * sizeof(int));
    float* bucket_w   = (float*)alloc((size_t)E_ * NTOK * sizeof(float));
    unsigned short* xb     = (unsigned short*)alloc((size_t)NTOK * D_ * sizeof(unsigned short));      // 4 MB
    unsigned short* w1b    = (unsigned short*)alloc((size_t)E_ * F_ * D_ * sizeof(unsigned short));   // 128 MB
    unsigned short* w2b    = (unsigned short*)alloc((size_t)E_ * D_ * F_ * sizeof(unsigned short));   // 128 MB
    unsigned short* hidden = (unsigned short*)alloc((size_t)NPAIR * F_ * sizeof(unsigned short));     // 64 MB

    hipMemsetAsync(d_out, 0, (size_t)out_size * sizeof(float), stream);

    router_kernel<<<NTOK, 256, 0, stream>>>(x, keys, rw, rb, topi, topw, counts);
    bucket_kernel<<<NPAIR / 256, 256, 0, stream>>>(topi, topw, counts, bucket_tok, bucket_w);
    scan_kernel<<<1, 64, 0, stream>>>(counts, offsets);

    cvt_kernel<<<(NTOK * D_) / 4096, 256, 0, stream>>>(x, xb);
    cvt_kernel<<<(E_ * F_ * D_) / 4096, 256, 0, stream>>>(w1, w1b);
    cvt_kernel<<<(E_ * D_ * F_) / 4096, 256, 0, stream>>>(w2, w2b);

    gemm1_kernel<<<dim3(F_ / 128, NTOK / 128, E_), 256, 0, stream>>>(
        xb, w1b, b1, counts, offsets, bucket_tok, hidden);
    gemm2_kernel<<<dim3(D_ / 128, NTOK / 128, E_), 256, 0, stream>>>(
        hidden, w2b, b2, counts, offsets, bucket_tok, bucket_w, out);
}